// Round 3
// baseline (824.001 us; speedup 1.0000x reference)
//
#include <hip/hip_runtime.h>
#include <hip/hip_bf16.h>
#include <stdint.h>

#define INPUT_DIM 1024
#define PRED_LEN 96
#define HIDDEN 512
#define BATCH 4096
#define W1_ROWS 1032  // INPUT_DIM + DAY_EMB

typedef __attribute__((ext_vector_type(8))) short bf16x8;
typedef __attribute__((ext_vector_type(4))) float floatx4;

__device__ __forceinline__ unsigned short f32_to_bf16_rne(float f) {
    union { float f; unsigned int u; } v; v.f = f;
    unsigned int u = v.u;
    unsigned int r = u + 0x7fffu + ((u >> 16) & 1u);
    return (unsigned short)(r >> 16);
}

__device__ __forceinline__ void async_copy16(const void* g, void* l) {
    __builtin_amdgcn_global_load_lds(
        (const __attribute__((address_space(1))) unsigned int*)g,
        (__attribute__((address_space(3))) unsigned int*)l, 16, 0, 0);
}

// ---------------------------------------------------------------- convert x
__global__ void convert_x_kernel(const float* __restrict__ x,
                                 unsigned short* __restrict__ xb) {
    int i = (blockIdx.x * 256 + threadIdx.x) * 4;
    float4 v = *reinterpret_cast<const float4*>(x + i);
    ushort4 o;
    o.x = f32_to_bf16_rne(v.x);
    o.y = f32_to_bf16_rne(v.y);
    o.z = f32_to_bf16_rne(v.z);
    o.w = f32_to_bf16_rne(v.w);
    *reinterpret_cast<ushort4*>(xb + i) = o;
}

// ------------------------------------------- transpose+convert W1x -> (p,n,k)
// Round-5 4x4 register-block transpose (harness-verified). Unchanged.
__global__ void transpose_w1_kernel(const float* __restrict__ W1,
                                    unsigned short* __restrict__ W1t) {
    __shared__ unsigned short tile[64 * 64];  // [n][k], swizzled chunks
    int bid = blockIdx.x;
    int nt = bid & 7;          // n tile (8 x 64)
    int kt = (bid >> 3) & 15;  // k tile (16 x 64)
    int p  = bid >> 7;
    int t  = threadIdx.x;
    const float* src = W1 + (size_t)p * W1_ROWS * HIDDEN;
    const int k0 = kt * 64, n0 = nt * 64;

    const int tn = t & 15;    // n-group
    const int tk = t >> 4;    // k-group 0..15
    float4 v[4];
    #pragma unroll
    for (int i = 0; i < 4; ++i)
        v[i] = *reinterpret_cast<const float4*>(src + (size_t)(k0 + 4 * tk + i) * HIDDEN + n0 + 4 * tn);
    const int slot1 = ((tk >> 2) ^ (tn & 3)) * 16 + (tk & 3) * 4;
    {
        ushort4 w0, w1, w2, w3;
        w0.x = f32_to_bf16_rne(v[0].x); w0.y = f32_to_bf16_rne(v[1].x);
        w0.z = f32_to_bf16_rne(v[2].x); w0.w = f32_to_bf16_rne(v[3].x);
        w1.x = f32_to_bf16_rne(v[0].y); w1.y = f32_to_bf16_rne(v[1].y);
        w1.z = f32_to_bf16_rne(v[2].y); w1.w = f32_to_bf16_rne(v[3].y);
        w2.x = f32_to_bf16_rne(v[0].z); w2.y = f32_to_bf16_rne(v[1].z);
        w2.z = f32_to_bf16_rne(v[2].z); w2.w = f32_to_bf16_rne(v[3].z);
        w3.x = f32_to_bf16_rne(v[0].w); w3.y = f32_to_bf16_rne(v[1].w);
        w3.z = f32_to_bf16_rne(v[2].w); w3.w = f32_to_bf16_rne(v[3].w);
        *reinterpret_cast<ushort4*>(tile + (4 * tn + 0) * 64 + slot1) = w0;
        *reinterpret_cast<ushort4*>(tile + (4 * tn + 1) * 64 + slot1) = w1;
        *reinterpret_cast<ushort4*>(tile + (4 * tn + 2) * 64 + slot1) = w2;
        *reinterpret_cast<ushort4*>(tile + (4 * tn + 3) * 64 + slot1) = w3;
    }
    __syncthreads();

    const int nr = t >> 2;
    const int q  = t & 3;
    const int slot2 = (q ^ ((nr >> 2) & 3)) * 16;
    uint4 a = *reinterpret_cast<const uint4*>(tile + nr * 64 + slot2);
    uint4 b = *reinterpret_cast<const uint4*>(tile + nr * 64 + slot2 + 8);
    size_t dst = ((size_t)p * HIDDEN + n0 + nr) * 1024 + k0 + q * 16;
    *reinterpret_cast<uint4*>(W1t + dst)     = a;
    *reinterpret_cast<uint4*>(W1t + dst + 8) = b;
}

// -------------------------------------------------- exact f32 bias precompute
__global__ void bias_kernel(const float* __restrict__ W1,
                            const float* __restrict__ day_emb,
                            const float* __restrict__ b1,
                            float* __restrict__ bias) {
    int p = blockIdx.x;
    int h = threadIdx.x;  // 512 threads
    const float* W1e = W1 + ((size_t)p * W1_ROWS + INPUT_DIM) * HIDDEN;
    float acc = b1[p * HIDDEN + h];
    #pragma unroll
    for (int e = 0; e < 8; ++e)
        acc += day_emb[p * 8 + e] * W1e[(size_t)e * HIDDEN + h];
    bias[p * HIDDEN + h] = acc;
}

// ------------------------------------- fused GEMM + relu + W2 reduction + b2
// Round-8: 3-slot LDS ring, counted vmcnt (T4), ONE barrier per K-step.
// BM=128, BN=256 (x2 nt), BK=64, 8 waves (2Mx4N), per-wave 64x64, acc[4][4].
// LDS: 3x(A 16KB + B 32KB) = 144 KB ring + 6 KB extras -> 1 block/CU.
// Per virtual K-step vkt (32 total; nt folded in, pipeline never drains):
//   vmcnt(6)   -- own vkt loads landed (6 = vkt+1's loads still in flight)
//   s_barrier  -- ALL waves' vkt loads landed; all readers of slot
//                 (vkt-1)%3 are past their reads (reads complete before a
//                 wave can reach the barrier: MFMA issue requires operands)
//   stage vkt+2 -> slot (vkt+2)%3 == (vkt-1)%3   (WAR-safe by the barrier)
//   16 ds_read_b128 + 32 MFMA from slot vkt%3
// Issue-to-wait distance ~2 K-steps (~2500cy) >> 900cy HBM latency.
// Round-2's failure mode (vmcnt(0) depth-1 + 8 barriers/K-tile = drain0
// variant, m218) is removed: 32 barriers/block, vmcnt never 0 in loop.
// Swizzle: round-0's measured-zero-conflict chunk-XOR, 128-B rows, linear
// lane*16 gload_lds dest, pre-swizzled global source. Full-line staging.
__global__ void __launch_bounds__(512, 2)
mlp_head_kernel(const unsigned short* __restrict__ xb,   // 4096x1024 bf16
                const unsigned short* __restrict__ W1t,  // 96x512x1024 bf16 (N-major)
                const float* __restrict__ bias,          // 96x512 f32
                const float* __restrict__ W2,            // 96x512 f32
                const float* __restrict__ b2,            // 96 f32
                float* __restrict__ out)                 // 4096x96 f32
{
    __shared__ unsigned short A_lds[3][128 * 64];  // 3 x 16 KB
    __shared__ unsigned short B_lds[3][256 * 64];  // 3 x 32 KB
    __shared__ float w2s[HIDDEN];
    __shared__ float biass[HIDDEN];
    __shared__ float red[4][128];

    const int mt   = blockIdx.x;   // 0..31 batch tile (128 rows)
    const int p    = blockIdx.y;   // 0..95
    const int t    = threadIdx.x;  // 0..511
    const int lane = t & 63;
    const int w    = t >> 6;       // 0..7
    const int wm   = w >> 2;       // 0..1  (M half: 64 rows)
    const int wn   = w & 3;        // 0..3  (N quarter: 64 cols)
    const int l15  = lane & 15;
    const int quad = lane >> 4;
    const int sl0  = (quad ^ (l15 & 7)) * 8;        // kk=0 chunk slot (shorts)
    const int sl1  = ((4 + quad) ^ (l15 & 7)) * 8;  // kk=1

    const int aro = (wm * 64 + l15) * 64;  // A frag row base (shorts)
    const int bro = (wn * 64 + l15) * 64;  // B frag row base

    // staging: thread t -> row tr=t>>3 (+part*64), LDS dest linear t*16B;
    // global src pre-swizzled by chunk (t&7)^(tr&7)  (part*64 keeps tr&7).
    const int tr   = t >> 3;                      // 0..63
    const int skc  = ((t & 7) ^ (tr & 7)) * 8;    // swizzled k-chunk (shorts)
    const int ldst = t * 8;                       // LDS dest (shorts)

    const int m0 = mt * 128;
    const unsigned short* agb = xb  + (size_t)(m0 + tr) * 1024 + skc;
    const unsigned short* bgb = W1t + ((size_t)p * HIDDEN + tr) * 1024 + skc;

    for (int i = t; i < HIDDEN; i += 512) {
        w2s[i]   = W2[p * HIDDEN + i];
        biass[i] = bias[p * HIDDEN + i];
    }

    float partial[4][4];
    #pragma unroll
    for (int i = 0; i < 4; ++i)
        #pragma unroll
        for (int r = 0; r < 4; ++r) partial[i][r] = 0.f;

    floatx4 acc[4][4];
    #pragma unroll
    for (int i = 0; i < 4; ++i)
        #pragma unroll
        for (int j = 0; j < 4; ++j)
            acc[i][j] = (floatx4){0.f, 0.f, 0.f, 0.f};

    // ---- prologue: stage vkt0 -> slot0, vkt1 -> slot1 (issue order matters)
    {
        async_copy16(agb,                 &A_lds[0][ldst]);
        async_copy16(agb + 65536,         &A_lds[0][4096 + ldst]);
        async_copy16(bgb,                 &B_lds[0][ldst]);
        async_copy16(bgb + 65536,         &B_lds[0][4096 + ldst]);
        async_copy16(bgb + 131072,        &B_lds[0][8192 + ldst]);
        async_copy16(bgb + 196608,        &B_lds[0][12288 + ldst]);
        async_copy16(agb + 64,            &A_lds[1][ldst]);
        async_copy16(agb + 65536 + 64,    &A_lds[1][4096 + ldst]);
        async_copy16(bgb + 64,            &B_lds[1][ldst]);
        async_copy16(bgb + 65536 + 64,    &B_lds[1][4096 + ldst]);
        async_copy16(bgb + 131072 + 64,   &B_lds[1][8192 + ldst]);
        async_copy16(bgb + 196608 + 64,   &B_lds[1][12288 + ldst]);
    }

    int cs = 0;  // compute slot = vkt % 3
    int ss = 2;  // stage slot   = (vkt+2) % 3

    #pragma unroll 1
    for (int vkt = 0; vkt < 31; ++vkt) {
        // own vkt loads landed (vkt+1's 6 may stay in flight)
        asm volatile("s_waitcnt vmcnt(6)" ::: "memory");
        __builtin_amdgcn_s_barrier();  // all waves' loads landed; slot ss free

        if (vkt < 30) {  // stage vkt+2 into slot ss
            const int v2 = vkt + 2;
            const int ko = (v2 & 15) << 6;
            const size_t no = (size_t)(v2 >> 4) * 262144;
            const unsigned short* a2 = agb + ko;
            const unsigned short* bq = bgb + no + ko;
            unsigned short* Ad = &A_lds[ss][ldst];
            unsigned short* Bd = &B_lds[ss][ldst];
            async_copy16(a2,           Ad);
            async_copy16(a2 + 65536,   Ad + 4096);
            async_copy16(bq,           Bd);
            async_copy16(bq + 65536,   Bd + 4096);
            async_copy16(bq + 131072,  Bd + 8192);
            async_copy16(bq + 196608,  Bd + 12288);
        }

        // compute slot cs: 16 ds_read_b128 + 32 MFMA
        {
            const unsigned short* Ab = &A_lds[cs][0];
            const unsigned short* Bb = &B_lds[cs][0];
            bf16x8 af[4][2], bf[2][2];
            #pragma unroll
            for (int i = 0; i < 4; ++i) {
                af[i][0] = *reinterpret_cast<const bf16x8*>(Ab + aro + i * 1024 + sl0);
                af[i][1] = *reinterpret_cast<const bf16x8*>(Ab + aro + i * 1024 + sl1);
            }
            #pragma unroll
            for (int j = 0; j < 2; ++j) {
                bf[j][0] = *reinterpret_cast<const bf16x8*>(Bb + bro + j * 1024 + sl0);
                bf[j][1] = *reinterpret_cast<const bf16x8*>(Bb + bro + j * 1024 + sl1);
            }
            __builtin_amdgcn_s_setprio(1);
            #pragma unroll
            for (int i = 0; i < 4; ++i)
                #pragma unroll
                for (int j = 0; j < 2; ++j) {
                    acc[i][j] = __builtin_amdgcn_mfma_f32_16x16x32_bf16(af[i][0], bf[j][0], acc[i][j], 0, 0, 0);
                    acc[i][j] = __builtin_amdgcn_mfma_f32_16x16x32_bf16(af[i][1], bf[j][1], acc[i][j], 0, 0, 0);
                }
            __builtin_amdgcn_s_setprio(0);
            #pragma unroll
            for (int j = 0; j < 2; ++j) {
                bf[j][0] = *reinterpret_cast<const bf16x8*>(Bb + bro + (j + 2) * 1024 + sl0);
                bf[j][1] = *reinterpret_cast<const bf16x8*>(Bb + bro + (j + 2) * 1024 + sl1);
            }
            __builtin_amdgcn_s_setprio(1);
            #pragma unroll
            for (int i = 0; i < 4; ++i)
                #pragma unroll
                for (int j = 0; j < 2; ++j) {
                    acc[i][j + 2] = __builtin_amdgcn_mfma_f32_16x16x32_bf16(af[i][0], bf[j][0], acc[i][j + 2], 0, 0, 0);
                    acc[i][j + 2] = __builtin_amdgcn_mfma_f32_16x16x32_bf16(af[i][1], bf[j][1], acc[i][j + 2], 0, 0, 0);
                }
            __builtin_amdgcn_s_setprio(0);
        }

        if (vkt == 15) {  // nt0 epilogue: fold acc into partial, re-zero
            #pragma unroll
            for (int j = 0; j < 4; ++j) {
                int c = wn * 64 + j * 16 + l15;
                float w2v = w2s[c];
                float bv  = biass[c];
                #pragma unroll
                for (int i = 0; i < 4; ++i)
                    #pragma unroll
                    for (int r = 0; r < 4; ++r) {
                        float hv = acc[i][j][r] + bv;
                        hv = hv > 0.f ? hv : 0.f;
                        partial[i][r] += hv * w2v;
                        acc[i][j][r] = 0.f;
                    }
            }
        }

        cs = (cs == 2) ? 0 : cs + 1;
        ss = (ss == 2) ? 0 : ss + 1;
    }

    // ---- peeled vkt=31 (cs=1): full drain, compute, nt1 epilogue
    asm volatile("s_waitcnt vmcnt(0)" ::: "memory");
    __builtin_amdgcn_s_barrier();
    {
        const unsigned short* Ab = &A_lds[1][0];
        const unsigned short* Bb = &B_lds[1][0];
        bf16x8 af[4][2], bf[2][2];
        #pragma unroll
        for (int i = 0; i < 4; ++i) {
            af[i][0] = *reinterpret_cast<const bf16x8*>(Ab + aro + i * 1024 + sl0);
            af[i][1] = *reinterpret_cast<const bf16x8*>(Ab + aro + i * 1024 + sl1);
        }
        #pragma unroll
        for (int j = 0; j < 2; ++j) {
            bf[j][0] = *reinterpret_cast<const bf16x8*>(Bb + bro + j * 1024 + sl0);
            bf[j][1] = *reinterpret_cast<const bf16x8*>(Bb + bro + j * 1024 + sl1);
        }
        #pragma unroll
        for (int i = 0; i < 4; ++i)
            #pragma unroll
            for (int j = 0; j < 2; ++j) {
                acc[i][j] = __builtin_amdgcn_mfma_f32_16x16x32_bf16(af[i][0], bf[j][0], acc[i][j], 0, 0, 0);
                acc[i][j] = __builtin_amdgcn_mfma_f32_16x16x32_bf16(af[i][1], bf[j][1], acc[i][j], 0, 0, 0);
            }
        #pragma unroll
        for (int j = 0; j < 2; ++j) {
            bf[j][0] = *reinterpret_cast<const bf16x8*>(Bb + bro + (j + 2) * 1024 + sl0);
            bf[j][1] = *reinterpret_cast<const bf16x8*>(Bb + bro + (j + 2) * 1024 + sl1);
        }
        #pragma unroll
        for (int i = 0; i < 4; ++i)
            #pragma unroll
            for (int j = 0; j < 2; ++j) {
                acc[i][j + 2] = __builtin_amdgcn_mfma_f32_16x16x32_bf16(af[i][0], bf[j][0], acc[i][j + 2], 0, 0, 0);
                acc[i][j + 2] = __builtin_amdgcn_mfma_f32_16x16x32_bf16(af[i][1], bf[j][1], acc[i][j + 2], 0, 0, 0);
            }
    }
    // nt1 epilogue
    #pragma unroll
    for (int j = 0; j < 4; ++j) {
        int c = 256 + wn * 64 + j * 16 + l15;
        float w2v = w2s[c];
        float bv  = biass[c];
        #pragma unroll
        for (int i = 0; i < 4; ++i)
            #pragma unroll
            for (int r = 0; r < 4; ++r) {
                float hv = acc[i][j][r] + bv;
                hv = hv > 0.f ? hv : 0.f;
                partial[i][r] += hv * w2v;
            }
    }

    // reduce over the 16 columns held by l15 lanes within each quad
    #pragma unroll
    for (int i = 0; i < 4; ++i)
        #pragma unroll
        for (int r = 0; r < 4; ++r) {
            float v = partial[i][r];
            v += __shfl_xor(v, 1);
            v += __shfl_xor(v, 2);
            v += __shfl_xor(v, 4);
            v += __shfl_xor(v, 8);
            partial[i][r] = v;
        }

    if (l15 == 0) {
        #pragma unroll
        for (int i = 0; i < 4; ++i)
            #pragma unroll
            for (int r = 0; r < 4; ++r) {
                int row = wm * 64 + i * 16 + quad * 4 + r;  // C: row = quad*4+reg
                red[wn][row] = partial[i][r];
            }
    }
    __syncthreads();
    if (t < 128) {
        float v = red[0][t] + red[1][t] + red[2][t] + red[3][t] + b2[p];
        out[(size_t)(m0 + t) * PRED_LEN + p] = v;
    }
}

// ---------------------------------------------------------------------------
extern "C" void kernel_launch(void* const* d_in, const int* in_sizes, int n_in,
                              void* d_out, int out_size, void* d_ws, size_t ws_size,
                              hipStream_t stream) {
    const float* x       = (const float*)d_in[0];
    const float* day_emb = (const float*)d_in[1];
    const float* W1      = (const float*)d_in[2];
    const float* b1      = (const float*)d_in[3];
    const float* W2      = (const float*)d_in[4];
    const float* b2      = (const float*)d_in[5];
    float* out = (float*)d_out;

    const size_t xb_bytes  = (size_t)BATCH * INPUT_DIM * 2;             // 8,388,608
    const size_t w1t_bytes = (size_t)PRED_LEN * HIDDEN * INPUT_DIM * 2; // 100,663,296
    const size_t bias_bytes = (size_t)PRED_LEN * HIDDEN * 4;            // 196,608
    if (ws_size < xb_bytes + w1t_bytes + bias_bytes) return;

    unsigned short* xb  = (unsigned short*)d_ws;
    unsigned short* w1t = (unsigned short*)((char*)d_ws + xb_bytes);
    float* biasp        = (float*)((char*)d_ws + xb_bytes + w1t_bytes);

    convert_x_kernel<<<(BATCH * INPUT_DIM) / (256 * 4), 256, 0, stream>>>(x, xb);
    transpose_w1_kernel<<<PRED_LEN * 16 * 8, 256, 0, stream>>>(W1, w1t);
    bias_kernel<<<PRED_LEN, HIDDEN, 0, stream>>>(W1, day_emb, b1, biasp);

    dim3 grid(BATCH / 128, PRED_LEN);
    mlp_head_kernel<<<grid, 512, 0, stream>>>(xb, w1t, biasp, W2, b2, out);
}

// Round 4
// 662.006 us; speedup vs baseline: 1.2447x; 1.2447x over previous
//
#include <hip/hip_runtime.h>
#include <hip/hip_bf16.h>
#include <stdint.h>

#define INPUT_DIM 1024
#define PRED_LEN 96
#define HIDDEN 512
#define BATCH 4096
#define W1_ROWS 1032  // INPUT_DIM + DAY_EMB

typedef __attribute__((ext_vector_type(8))) short bf16x8;
typedef __attribute__((ext_vector_type(4))) float floatx4;

__device__ __forceinline__ unsigned short f32_to_bf16_rne(float f) {
    union { float f; unsigned int u; } v; v.f = f;
    unsigned int u = v.u;
    unsigned int r = u + 0x7fffu + ((u >> 16) & 1u);
    return (unsigned short)(r >> 16);
}

__device__ __forceinline__ unsigned int pack_bf16x2(float lo, float hi) {
    return (unsigned int)f32_to_bf16_rne(lo) | ((unsigned int)f32_to_bf16_rne(hi) << 16);
}

__device__ __forceinline__ void async_copy16(const void* g, void* l) {
    __builtin_amdgcn_global_load_lds(
        (const __attribute__((address_space(1))) unsigned int*)g,
        (__attribute__((address_space(3))) unsigned int*)l, 16, 0, 0);
}

// ---------------------------------------------------------------- convert x
// Round-9: widened to 16-B stores (2x float4 -> 8 bf16 per thread).
__global__ void convert_x_kernel(const float* __restrict__ x,
                                 unsigned short* __restrict__ xb) {
    int i = (blockIdx.x * 256 + threadIdx.x) * 8;
    float4 a = *reinterpret_cast<const float4*>(x + i);
    float4 b = *reinterpret_cast<const float4*>(x + i + 4);
    uint4 o;
    o.x = pack_bf16x2(a.x, a.y);
    o.y = pack_bf16x2(a.z, a.w);
    o.z = pack_bf16x2(b.x, b.y);
    o.w = pack_bf16x2(b.z, b.w);
    *reinterpret_cast<uint4*>(xb + i) = o;
}

// ------------------------------------------- transpose+convert W1x -> (p,n,k)
// Round-9 rewrite: pure-register 4n x 8k per-thread transpose. No LDS, no
// __syncthreads, 6144 blocks (was 12288 + LDS round-trip whose b128 read
// phase used only 16 of 32 banks). Per thread: 8 coalesced float4 row reads
// (16 lanes x 256 B per row-segment), 32 bf16 packs, 4 coalesced 16-B stores
// (4 lanes x 16 B = 64-B segments per n-row).
// Block tile: 64 n x 128 k. grid = p(96) x kt(8) x nt(8).
__global__ void transpose_w1_kernel(const float* __restrict__ W1,
                                    unsigned short* __restrict__ W1t) {
    const int bid = blockIdx.x;
    const int nt = bid & 7;          // n tile (64)
    const int kt = (bid >> 3) & 7;   // k tile (128)
    const int p  = bid >> 6;
    const int t  = threadIdx.x;
    const int tn = t & 15;           // n-group: cols n0 + 4*tn .. +3
    const int tk = t >> 4;           // k-group: rows k0 + 8*tk .. +7
    const int n0 = nt * 64;
    const int k0 = kt * 128;

    const float* src = W1 + (size_t)p * W1_ROWS * HIDDEN
                          + (size_t)(k0 + 8 * tk) * HIDDEN + n0 + 4 * tn;
    float4 v[8];
    #pragma unroll
    for (int i = 0; i < 8; ++i)
        v[i] = *reinterpret_cast<const float4*>(src + (size_t)i * HIDDEN);

    // output row n0+4*tn+j gets k-chunk [k0+8*tk .. +8)
    size_t dst = ((size_t)p * HIDDEN + n0 + 4 * tn) * 1024 + k0 + 8 * tk;
    #pragma unroll
    for (int j = 0; j < 4; ++j) {
        float c[8];
        #pragma unroll
        for (int i = 0; i < 8; ++i)
            c[i] = (j == 0) ? v[i].x : (j == 1) ? v[i].y : (j == 2) ? v[i].z : v[i].w;
        uint4 o;
        o.x = pack_bf16x2(c[0], c[1]);
        o.y = pack_bf16x2(c[2], c[3]);
        o.z = pack_bf16x2(c[4], c[5]);
        o.w = pack_bf16x2(c[6], c[7]);
        *reinterpret_cast<uint4*>(W1t + dst + (size_t)j * 1024) = o;
    }
}

// -------------------------------------------------- exact f32 bias precompute
__global__ void bias_kernel(const float* __restrict__ W1,
                            const float* __restrict__ day_emb,
                            const float* __restrict__ b1,
                            float* __restrict__ bias) {
    int p = blockIdx.x;
    int h = threadIdx.x;  // 512 threads
    const float* W1e = W1 + ((size_t)p * W1_ROWS + INPUT_DIM) * HIDDEN;
    float acc = b1[p * HIDDEN + h];
    #pragma unroll
    for (int e = 0; e < 8; ++e)
        acc += day_emb[p * 8 + e] * W1e[(size_t)e * HIDDEN + h];
    bias[p * HIDDEN + h] = acc;
}

// ------------------------------------- fused GEMM + relu + W2 reduction + b2
// Round-9: EXACT revert to the round-0 kernel (measured 385 us, MfmaUtil
// 51.7%, 0 bank conflicts, FETCH 422 MB). Rounds 6-8 (dbuf BK=32, 8-phase
// 256^2, ring-3 counted-vmcnt) all regressed: with K=1024 (16-32 K-steps),
// N=512 and a heavy per-block epilogue, deep intra-block pipelines never
// amortize and sacrifice the 3-block/CU inter-block overlap (m114) that this
// simple 2-barrier structure relies on. Do not re-attempt without new
// evidence. Note: acc[4][4] lives in AGPRs (CSV VGPR=76 excludes them);
// total regs ~140 -> (256,4)'s 128-reg cap spills (prior session evidence).
__global__ void __launch_bounds__(256, 3)
mlp_head_kernel(const unsigned short* __restrict__ xb,   // 4096x1024 bf16
                const unsigned short* __restrict__ W1t,  // 96x512x1024 bf16 (N-major)
                const float* __restrict__ bias,          // 96x512 f32
                const float* __restrict__ W2,            // 96x512 f32
                const float* __restrict__ b2,            // 96 f32
                float* __restrict__ out)                 // 4096x96 f32
{
    __shared__ unsigned short As[128 * 64];
    __shared__ unsigned short Bs[128 * 64];
    __shared__ float w2s[HIDDEN];
    __shared__ float biass[HIDDEN];
    __shared__ float red[2][128];

    const int mt   = blockIdx.x;  // 0..31 batch tile
    const int p    = blockIdx.y;  // 0..95
    const int t    = threadIdx.x;
    const int lane = t & 63;
    const int w    = t >> 6;
    const int wi   = w >> 1;      // row half (64)
    const int wj   = w & 1;       // col half (64)
    const int l15  = lane & 15;
    const int quad = lane >> 4;
    const int xl   = l15 & 7;     // row&7 for all this lane's fragment rows

    // staging constants: thread stages LDS slot (row, t&7) with global chunk
    // (t&7)^(row&7); row = c*32 + (t>>3)
    const int t3    = t >> 3;                    // 0..31
    const int skc   = ((t & 7) ^ (t3 & 7)) * 8;  // swizzled k-offset (elems)
    const int ldsq8 = t * 8;                     // per-c LDS offset adds 2048

    for (int i = t; i < HIDDEN; i += 256) {
        w2s[i]   = W2[p * HIDDEN + i];
        biass[i] = bias[p * HIDDEN + i];
    }

    const int m0 = mt * 128;
    const unsigned short* ag = xb  + (size_t)m0 * 1024 + (size_t)t3 * 1024 + skc;
    const unsigned short* bg = W1t + (size_t)p * HIDDEN * 1024 + (size_t)t3 * 1024 + skc;

    float partial[4][4];
    #pragma unroll
    for (int i = 0; i < 4; ++i)
        #pragma unroll
        for (int r = 0; r < 4; ++r) partial[i][r] = 0.f;

    for (int nt = 0; nt < 4; ++nt) {
        floatx4 acc[4][4];
        #pragma unroll
        for (int i = 0; i < 4; ++i)
            #pragma unroll
            for (int j = 0; j < 4; ++j)
                acc[i][j] = (floatx4){0.f, 0.f, 0.f, 0.f};

        const size_t bn = (size_t)nt * 128 * 1024;  // n-tile offset in W1t

        for (int k0 = 0; k0 < 1024; k0 += 64) {
            __syncthreads();  // prior K-step's ds_reads complete
            #pragma unroll
            for (int c = 0; c < 4; ++c) {
                async_copy16(ag + (size_t)c * 32 * 1024 + k0,      As + ldsq8 + c * 2048);
                async_copy16(bg + bn + (size_t)c * 32 * 1024 + k0, Bs + ldsq8 + c * 2048);
            }
            __syncthreads();  // staging visible (vmcnt drained by barrier)
            #pragma unroll
            for (int kk = 0; kk < 2; ++kk) {
                const int slot = (kk * 4 + quad) ^ xl;  // swizzled chunk position
                bf16x8 af[4], bfr[4];
                #pragma unroll
                for (int i = 0; i < 4; ++i) {
                    int r = wi * 64 + i * 16 + l15;
                    af[i] = *reinterpret_cast<const bf16x8*>(As + r * 64 + slot * 8);
                }
                #pragma unroll
                for (int j = 0; j < 4; ++j) {
                    int n = wj * 64 + j * 16 + l15;
                    bfr[j] = *reinterpret_cast<const bf16x8*>(Bs + n * 64 + slot * 8);
                }
                #pragma unroll
                for (int i = 0; i < 4; ++i)
                    #pragma unroll
                    for (int j = 0; j < 4; ++j)
                        acc[i][j] = __builtin_amdgcn_mfma_f32_16x16x32_bf16(
                            af[i], bfr[j], acc[i][j], 0, 0, 0);
            }
        }

        // epilogue for this n-tile: bias + relu + weight by W2, fold into partials
        const int n0 = nt * 128;
        #pragma unroll
        for (int j = 0; j < 4; ++j) {
            int c = n0 + wj * 64 + j * 16 + l15;  // C layout: col = lane&15
            float w2v = w2s[c];
            float bv  = biass[c];
            #pragma unroll
            for (int i = 0; i < 4; ++i)
                #pragma unroll
                for (int r = 0; r < 4; ++r) {
                    float hv = acc[i][j][r] + bv;
                    hv = hv > 0.f ? hv : 0.f;
                    partial[i][r] += hv * w2v;
                }
        }
    }

    // reduce over columns: 16 lanes of each quad hold distinct cols of same rows
    #pragma unroll
    for (int i = 0; i < 4; ++i)
        #pragma unroll
        for (int r = 0; r < 4; ++r) {
            float v = partial[i][r];
            v += __shfl_xor(v, 1);
            v += __shfl_xor(v, 2);
            v += __shfl_xor(v, 4);
            v += __shfl_xor(v, 8);
            partial[i][r] = v;
        }

    if (l15 == 0) {
        #pragma unroll
        for (int i = 0; i < 4; ++i)
            #pragma unroll
            for (int r = 0; r < 4; ++r) {
                int row = wi * 64 + i * 16 + quad * 4 + r;  // C layout: row = quad*4+reg
                red[wj][row] = partial[i][r];
            }
    }
    __syncthreads();
    if (t < 128) {
        float v = red[0][t] + red[1][t] + b2[p];
        out[(size_t)(m0 + t) * PRED_LEN + p] = v;
    }
}

// ---------------------------------------------------------------------------
extern "C" void kernel_launch(void* const* d_in, const int* in_sizes, int n_in,
                              void* d_out, int out_size, void* d_ws, size_t ws_size,
                              hipStream_t stream) {
    const float* x       = (const float*)d_in[0];
    const float* day_emb = (const float*)d_in[1];
    const float* W1      = (const float*)d_in[2];
    const float* b1      = (const float*)d_in[3];
    const float* W2      = (const float*)d_in[4];
    const float* b2      = (const float*)d_in[5];
    float* out = (float*)d_out;

    const size_t xb_bytes  = (size_t)BATCH * INPUT_DIM * 2;             // 8,388,608
    const size_t w1t_bytes = (size_t)PRED_LEN * HIDDEN * INPUT_DIM * 2; // 100,663,296
    const size_t bias_bytes = (size_t)PRED_LEN * HIDDEN * 4;            // 196,608
    if (ws_size < xb_bytes + w1t_bytes + bias_bytes) return;

    unsigned short* xb  = (unsigned short*)d_ws;
    unsigned short* w1t = (unsigned short*)((char*)d_ws + xb_bytes);
    float* biasp        = (float*)((char*)d_ws + xb_bytes + w1t_bytes);

    convert_x_kernel<<<(BATCH * INPUT_DIM) / (256 * 8), 256, 0, stream>>>(x, xb);
    transpose_w1_kernel<<<PRED_LEN * 8 * 8, 256, 0, stream>>>(W1, w1t);
    bias_kernel<<<PRED_LEN, HIDDEN, 0, stream>>>(W1, day_emb, b1, biasp);

    dim3 grid(BATCH / 128, PRED_LEN);
    mlp_head_kernel<<<grid, 256, 0, stream>>>(xb, w1t, biasp, W2, b2, out);
}